// Round 3
// baseline (117.409 us; speedup 1.0000x reference)
//
#include <hip/hip_runtime.h>
#include <stdint.h>

// ---------------------------------------------------------------------------
// B=2048, F0=40, D=32, LAYER0=LAYER1=128.  Rows r=b*32+d (65536).
//   phase0: h0[r,s] = relu(sum_{i<40,j<40} X[r,i]X[r,j] W0[i,j,s] + b0[s])
//   phase1: d1[r,s] = relu(sum_{i<40,j<64} X[r,i]NH[r,j] W1[i,j,s] + b1[s])
//   out[b,0:64] = sum_d h0[:,64:128]; out[b,64:192] = sum_d d1
//
// Round-12: KILL THE SPILL.  r11 ((512,4), 2 blocks/CU) showed VGPR 64 +
// WRITE_SIZE 1536->4608KB: the 128-unified cap split 64 arch + 64 acc and
// spilled ~8 arch regs; inner-loop scratch reloads (L2 ~200cy) ate the
// occupancy gain (54us, MfmaUtil 48%).  Fix: shrink arch live set under 64:
//   (a) xi_pk[10]: mt0 in lo half, mt1 in hi half (10 regs, was xi2[2][10]
//       = 20).  Broadcasts rebuilt per tile ({lo,lo},{hi,hi} -> VOP3P
//       op_sel foldable).
//   (b) av computed once per tile (av0/av1, 8 regs); bv rolled one nt at a
//       time (4 live + in-flight) instead of bv[4]=16.
// Arch estimate ~50-56 <= 64 -> no spill, 4 waves/SIMD from two DESYNCED
// blocks (LDS 76KB x2 = 152 <= 160KB).
// Carried: conflict-free W layout [sh][nt][lane][oct] (identity
// global_load_lds staging, lane-linear ds_read_b128), symmetrized W0 with
// triangular tile drop (30 tiles), 3-tile periods, phase1 pad tile 80
// (zero W; jv reads zeroed NH cols 64..71), fp16 datapath.
// ---------------------------------------------------------------------------

typedef __attribute__((ext_vector_type(8))) _Float16 half8;
typedef __attribute__((ext_vector_type(2))) _Float16 half2v;
typedef __attribute__((ext_vector_type(4))) float f32x4;

#define T0 30        // phase0 tiles after triangular drop
#define T1P 81       // phase1 tiles incl. 1 zero pad tile (80 real)
#define PERIOD 3
#define WBUF 12288   // halfwords per Wb buffer (3 tiles x 4096)

// phase-0 triangular schedule: jc blocks of sizes 2,4,6,8,10 (starts 0,2,6,12,20)
__host__ __device__ constexpr int ic0_of(int t) {
    return (t < 2) ? t : (t < 6) ? (t - 2) : (t < 12) ? (t - 6)
         : (t < 20) ? (t - 12) : (t - 20);
}
__host__ __device__ constexpr int jc0_of(int t) {
    return (t < 2) ? 0 : (t < 6) ? 1 : (t < 12) ? 2 : (t < 20) ? 3 : 4;
}

__device__ __forceinline__ unsigned short f2h(float f) {   // v_cvt_f16_f32, RNE
    return __builtin_bit_cast(unsigned short, (_Float16)f);
}
__device__ __forceinline__ float qsum(float v) {  // reduce across row-quads
    v += __shfl_xor(v, 16, 64);
    v += __shfl_xor(v, 32, 64);
    return v;
}
// async global->LDS DMA, 16 B/lane.  lds dest = (wave-uniform base) + lane*16.
__device__ __forceinline__ void gl_lds16(const unsigned short* g, unsigned short* l) {
    __builtin_amdgcn_global_load_lds(
        (const __attribute__((address_space(1))) unsigned int*)g,
        (__attribute__((address_space(3))) unsigned int*)l,
        16, 0, 0);
}

// ---------------------------------------------------------------------------
// Permute W -> Wp[t][ halfword pos = sh*2048 + nt*512 + lane*8 + oc ], where
// lane = kc*16+ml encodes (s = sh*64+nt*16+ml, k-octet kc), oc = k within
// octet.  Element = W[i = ic*4+kc][j = jc*8+oc][s].  Exactly the compute
// read order (16B/lane, lane-linear) -> conflict-free ds_read_b128 AND
// identity global_load_lds staging.  Phase0 tiles: symmetrized triangular
// Wsym.  Phase1 tile 80 = zeros (pad).  111 blocks x 256 threads.
// ---------------------------------------------------------------------------
__global__ void permute_w_both(const float* __restrict__ W0, const float* __restrict__ W1,
                               unsigned short* __restrict__ Wp0, unsigned short* __restrict__ Wp1)
{
    const int t = blockIdx.x;
    const int tid = threadIdx.x;
    unsigned short outv[16];
    unsigned short* dst;
    if (t < T0) {
        const int ic = ic0_of(t), jc = jc0_of(t);
        #pragma unroll
        for (int q = 0; q < 16; ++q) {
            int pos  = tid * 16 + q;
            int oc   = pos & 7, lane = (pos >> 3) & 63;
            int nt   = (pos >> 9) & 3, sh = pos >> 11;
            int s    = sh * 64 + nt * 16 + (lane & 15);
            int i    = ic * 4 + (lane >> 4), j = jc * 8 + oc;
            float v = 0.0f;                                   // i>j: folded into (j,i)
            if (i < j)       v = W0[((size_t)(i * 40 + j)) * 128 + s]
                               + W0[((size_t)(j * 40 + i)) * 128 + s];
            else if (i == j) v = W0[((size_t)(i * 40 + i)) * 128 + s];
            outv[q] = f2h(v);
        }
        dst = Wp0 + (size_t)t * 4096 + tid * 16;
    } else {
        const int tt = t - T0;
        if (tt == 80) {                                       // zero pad tile
            #pragma unroll
            for (int q = 0; q < 16; ++q) outv[q] = 0;
        } else {
            const int jc = tt / 10, ic = tt % 10;
            #pragma unroll
            for (int q = 0; q < 16; ++q) {
                int pos  = tid * 16 + q;
                int oc   = pos & 7, lane = (pos >> 3) & 63;
                int nt   = (pos >> 9) & 3, sh = pos >> 11;
                int s    = sh * 64 + nt * 16 + (lane & 15);
                int i    = ic * 4 + (lane >> 4), j = jc * 8 + oc;
                outv[q] = f2h(W1[((size_t)(i * 64 + j)) * 128 + s]);
            }
        }
        dst = Wp1 + (size_t)tt * 4096 + tid * 16;
    }
    *(uint4*)dst       = *(const uint4*)outv;
    *(uint4*)(dst + 8) = *(const uint4*)(outv + 8);
}

// One GEMM phase.  Flat compile-time tile schedule, 3-tile periods, W staged
// via global_load_lds (double-buffered periods), one barrier per period.
// Phase1 t=80 is the pad: ic=0, jc=8; its jv reads NH cols 64..71 (zeroed).
// Register-lean datapath: xi_pk (10 regs, mt0=lo/mt1=hi), av0/av1 built once
// per tile, bv rolled per nt.
template<int T, int PHASE>
__device__ __forceinline__ void gemm_phase(
    const unsigned short* __restrict__ Wp,   // [T][4096] fp16, global, read-order layout
    const unsigned short* __restrict__ Jl,   // LDS j-source (Xl or NH)
    int jstride,                             // row stride of Jl in elems
    const unsigned int xi_pk[10],            // X[r_mt0,i] | X[r_mt1,i]<<16 per ic*4+kc
    unsigned short* Wb,                      // LDS W double buffer [2][WBUF]
    f32x4 acc[2][4], int tid)
{
    const int lane = tid & 63;
    const int wv = tid >> 6;                 // wave id 0..7
    const int rt = wv & 3;                   // row-tile (32 rows)
    const int sh = wv >> 2;                  // s-half (64 cols)
    const int ml = lane & 15;

    const unsigned short* jrow0 = Jl + (rt * 32 + ml) * jstride;
    const unsigned short* jrow1 = jrow0 + 16 * jstride;

    // conflict-free bv base: per-(sh,nt) 1KB chunk, addr = base + lane*16B
    const unsigned short* brd = Wb + sh * 2048 + lane * 8;
    // DMA: global src per-lane = Wp + tile*4096 + tid*8 (halfwords);
    //      LDS dest wave-uniform = Wb + buf*WBUF + u*4096 + wv*512.
    const unsigned short* gsrc = Wp + tid * 8;
    unsigned short* ldst = Wb + wv * 512;

    auto stage_period = [&](int buf, int t0) {   // issue 3 tile DMAs
        #pragma unroll
        for (int u = 0; u < PERIOD; ++u)
            gl_lds16(gsrc + (size_t)(t0 + u) * 4096, ldst + buf * WBUF + u * 4096);
    };

    stage_period(0, 0);          // period 0 -> buf0
    __syncthreads();             // tiles landed

    uint4 jv0, jv1;
    constexpr int NP = T / PERIOD;
    #pragma unroll
    for (int p = 0; p < NP; ++p) {
        const int cb = p & 1;                            // compute buffer
        const int nb = cb ^ 1;
        if ((p + 1) * PERIOD < T) stage_period(nb, (p + 1) * PERIOD);
        #pragma unroll
        for (int u = 0; u < PERIOD; ++u) {
            const int t  = p * PERIOD + u;               // compile-time
            const int ic = (PHASE == 0) ? ic0_of(t) : (t % 10);
            const int jc = (PHASE == 0) ? jc0_of(t) : (t / 10);
            const bool rl = (t == 0) ||
                (jc != ((PHASE == 0) ? jc0_of(t - 1) : ((t - 1) / 10)));
            if (rl) {                                    // jv reload (jc changed)
                jv0 = *(const uint4*)(jrow0 + jc * 8);
                jv1 = *(const uint4*)(jrow1 + jc * 8);
            }
            // rebuild broadcast x for the two row-subtiles (op_sel-foldable)
            half2v xp = __builtin_bit_cast(half2v, xi_pk[ic]);
            half2v x0 = {xp[0], xp[0]};
            half2v x1 = {xp[1], xp[1]};
            uint4 av0, av1;
            av0.x = __builtin_bit_cast(unsigned int, (half2v)(x0 * __builtin_bit_cast(half2v, jv0.x)));
            av0.y = __builtin_bit_cast(unsigned int, (half2v)(x0 * __builtin_bit_cast(half2v, jv0.y)));
            av0.z = __builtin_bit_cast(unsigned int, (half2v)(x0 * __builtin_bit_cast(half2v, jv0.z)));
            av0.w = __builtin_bit_cast(unsigned int, (half2v)(x0 * __builtin_bit_cast(half2v, jv0.w)));
            av1.x = __builtin_bit_cast(unsigned int, (half2v)(x1 * __builtin_bit_cast(half2v, jv1.x)));
            av1.y = __builtin_bit_cast(unsigned int, (half2v)(x1 * __builtin_bit_cast(half2v, jv1.y)));
            av1.z = __builtin_bit_cast(unsigned int, (half2v)(x1 * __builtin_bit_cast(half2v, jv1.z)));
            av1.w = __builtin_bit_cast(unsigned int, (half2v)(x1 * __builtin_bit_cast(half2v, jv1.w)));
            #pragma unroll
            for (int nt = 0; nt < 4; ++nt) {             // bv rolled: 4 regs live/nt
                uint4 bv = *(const uint4*)(brd + cb * WBUF + u * 4096 + nt * 512);
                acc[0][nt] = __builtin_amdgcn_mfma_f32_16x16x32_f16(
                    __builtin_bit_cast(half8, av0),
                    __builtin_bit_cast(half8, bv), acc[0][nt], 0, 0, 0);
                acc[1][nt] = __builtin_amdgcn_mfma_f32_16x16x32_f16(
                    __builtin_bit_cast(half8, av1),
                    __builtin_bit_cast(half8, bv), acc[1][nt], 0, 0, 0);
            }
        }
        __syncthreads();     // nb DMA landed; cb reads done
    }
}

__global__ __launch_bounds__(512, 4)
void fused_two_layer(const float* __restrict__ x,
                     const unsigned short* __restrict__ W0p,
                     const float* __restrict__ b0,
                     const unsigned short* __restrict__ W1p,
                     const float* __restrict__ b1,
                     float* __restrict__ out)
{
    __shared__ __align__(16) unsigned short Xl[128 * 40];   // 10.0 KB
    __shared__ __align__(16) unsigned short NH[128 * 72];   // 18.0 KB (stride 72
        // -> 144B rows: b128 j-reads 2-way max = free; cols 64..71 zero pad)
    __shared__ __align__(16) unsigned short Wb[2 * WBUF];   // 48.0 KB W dbuf
    // total 76.0 KB -> 2 blocks/CU

    const int tid  = threadIdx.x;
    const int lane = tid & 63;
    const int wv   = tid >> 6;
    const int rt   = wv & 3;            // row-tile (32 rows)
    const int sh   = wv >> 2;           // s-half (64 cols)
    const int ml   = lane & 15;
    const int kc   = lane >> 4;

    // ---- stage X: x[4b][i][d] fp32 -> Xl[(bl*32+d)*40 + i] fp16 (RNE) ----
    const float* xblk = x + (size_t)blockIdx.x * (4 * 40 * 32);
    #pragma unroll
    for (int k = 0; k < 10; ++k) {
        int f = 512 * k + tid;          // 0..5119, coalesced
        int bl = f / 1280, rem = f - bl * 1280;
        int i = rem >> 5, d = rem & 31;
        Xl[(bl * 32 + d) * 40 + i] = f2h(xblk[f]);
    }
    __syncthreads();

    // ---- preload this lane's i-scalars, packed: mt0 lo half, mt1 hi half ----
    unsigned int xi_pk[10];
    {
        const unsigned short* xr0 = Xl + (rt * 32 + ml) * 40;
        const unsigned short* xr1 = xr0 + 16 * 40;
        #pragma unroll
        for (int ic = 0; ic < 10; ++ic) {
            unsigned int u0 = xr0[ic * 4 + kc];
            unsigned int u1 = xr1[ic * 4 + kc];
            xi_pk[ic] = u0 | (u1 << 16);
        }
    }

    f32x4 acc[2][4];
    const f32x4 zero4 = {0.f, 0.f, 0.f, 0.f};
    #pragma unroll
    for (int mt = 0; mt < 2; ++mt)
        #pragma unroll
        for (int nt = 0; nt < 4; ++nt) acc[mt][nt] = zero4;

    // ========== phase 0: 30 triangular tiles (Wsym), j from X ==========
    gemm_phase<T0, 0>(W0p, Xl, 40, xi_pk, Wb, acc, tid);

    {   // epilogue 0: bias+relu; sh==0 (s<64) -> NH; sh==1 -> d-sum -> out[:,0:64]
        float bias[4];
        #pragma unroll
        for (int nt = 0; nt < 4; ++nt) bias[nt] = b0[sh * 64 + nt * 16 + ml];
        if (sh == 0) {
            #pragma unroll
            for (int mt = 0; mt < 2; ++mt) {
                int r = rt * 32 + mt * 16 + (kc << 2);
                #pragma unroll
                for (int nt = 0; nt < 4; ++nt) {
                    int s = nt * 16 + ml;
                    #pragma unroll
                    for (int rg = 0; rg < 4; ++rg) {
                        float v = fmaxf(acc[mt][nt][rg] + bias[nt], 0.0f);
                        NH[(r + rg) * 72 + s] = f2h(v);
                    }
                }
            }
            // zero NH pad cols 64..71 for this wave's 32 rows (jc=8 pad tile)
            {
                int rp = rt * 32 + (lane >> 1);
                int a  = rp * 72 + 64 + (lane & 1) * 4;
                *(unsigned int*)&NH[a]     = 0u;
                *(unsigned int*)&NH[a + 2] = 0u;
            }
        } else {
            int bb = blockIdx.x * 4 + rt;
            #pragma unroll
            for (int nt = 0; nt < 4; ++nt) {
                float sA = 0.f;
                #pragma unroll
                for (int rg = 0; rg < 4; ++rg)
                    sA += fmaxf(acc[0][nt][rg] + bias[nt], 0.f)
                        + fmaxf(acc[1][nt][rg] + bias[nt], 0.f);
                sA = qsum(sA);
                if (lane < 16)
                    out[(size_t)bb * 192 + nt * 16 + lane] = sA;   // col = s-64
            }
        }
    }
    __syncthreads();   // NH (incl. pad zeros) visible to all waves

    #pragma unroll
    for (int mt = 0; mt < 2; ++mt)
        #pragma unroll
        for (int nt = 0; nt < 4; ++nt) acc[mt][nt] = zero4;

    // ========== phase 1: 81 tiles (80 real + pad), j from NH ==========
    gemm_phase<T1P, 1>(W1p, NH, 72, xi_pk, Wb, acc, tid);

    {   // epilogue 1: bias+relu; d-sum -> out[:, 64:192]
        float bias[4];
        #pragma unroll
        for (int nt = 0; nt < 4; ++nt) bias[nt] = b1[sh * 64 + nt * 16 + ml];
        int bb = blockIdx.x * 4 + rt;
        #pragma unroll
        for (int nt = 0; nt < 4; ++nt) {
            float sA = 0.f;
            #pragma unroll
            for (int rg = 0; rg < 4; ++rg)
                sA += fmaxf(acc[0][nt][rg] + bias[nt], 0.f)
                    + fmaxf(acc[1][nt][rg] + bias[nt], 0.f);
            sA = qsum(sA);
            if (lane < 16)
                out[(size_t)bb * 192 + 64 + sh * 64 + nt * 16 + lane] = sA;
        }
    }
}

extern "C" void kernel_launch(void* const* d_in, const int* in_sizes, int n_in,
                              void* d_out, int out_size, void* d_ws, size_t ws_size,
                              hipStream_t stream) {
    const float* x  = (const float*)d_in[0];   // [2048][40][32]
    const float* W0 = (const float*)d_in[1];   // [40][40][128]
    const float* b0 = (const float*)d_in[2];   // [128]
    const float* W1 = (const float*)d_in[3];   // [40][64][128]
    const float* b1 = (const float*)d_in[4];   // [128]
    float* out = (float*)d_out;                // [2048][192]

    unsigned short* W0p = (unsigned short*)d_ws;                          // T0*8192  = 245760 B
    unsigned short* W1p = (unsigned short*)((char*)d_ws + T0 * 4096 * 2); // T1P*8192 = 663552 B

    permute_w_both<<<T0 + T1P, 256, 0, stream>>>(W0, W1, W0p, W1p);
    fused_two_layer<<<512, 512, 0, stream>>>(x, W0p, b0, W1p, b1, out);
}